// Round 2
// baseline (175.964 us; speedup 1.0000x reference)
//
#include <hip/hip_runtime.h>
#include <hip/hip_bf16.h>

#define NUM_GT 25
#define NUM_PRED 40
#define NGT1 26        // gt labels 0..25
#define NPRED1 41      // pred labels 0..40
#define WAVES 4
#define BLOCK 256

// ws layout (u32 words):
//   [0  .. 25 ] gt_sizes[b]    (|gt == b|)
//   [32 .. 72 ] pred_sizes[p]  (|pred == p|)
//   [80 .. 120] ovl[p]         (bitmask over gt labels 0..25)
#define WS_GT   0
#define WS_PRED 32
#define WS_OVL  80
#define WS_WORDS 128

// ---------------------------------------------------------------------------
// Kernel 1: atomic-free per-lane-column histograms + test-then-set overlap.
//   sgt/spr: u16 counter, (bin b, lane l) at index b*64+l.
//   byte addr = b*128 + l*2 -> bank = (l/2)%32, independent of b:
//   always 2 lanes/bank (free), no data-dependent conflicts, no RMW races
//   (each lane owns its halfword column).
// ---------------------------------------------------------------------------
__global__ __launch_bounds__(BLOCK) void hist_kernel(
    const float* __restrict__ pred, const int* __restrict__ gt,
    unsigned int* __restrict__ ws, int n)
{
    __shared__ unsigned short sgt[WAVES][NGT1][64];    // 13,312 B
    __shared__ unsigned short spr[WAVES][NPRED1][64];  // 20,992 B
    __shared__ unsigned int   sovl[NPRED1];            //    164 B

    const int tid  = threadIdx.x;
    const int lane = tid & 63;
    const int wave = tid >> 6;

    // zero LDS
    unsigned int* z1 = (unsigned int*)sgt;
    for (int i = tid; i < (int)(sizeof(sgt) / 4); i += BLOCK) z1[i] = 0u;
    unsigned int* z2 = (unsigned int*)spr;
    for (int i = tid; i < (int)(sizeof(spr) / 4); i += BLOCK) z2[i] = 0u;
    if (tid < NPRED1) sovl[tid] = 0u;
    __syncthreads();

    unsigned short* gl = &sgt[wave][0][lane];  // + b*64 per bin
    unsigned short* pl = &spr[wave][0][lane];

    const int gtid   = blockIdx.x * BLOCK + tid;
    const int stride = gridDim.x * BLOCK;
    const int n4 = n >> 2;
    const float4* __restrict__ p4 = (const float4*)pred;
    const int4* __restrict__  g4 = (const int4*)gt;

    #pragma unroll 2
    for (int i = gtid; i < n4; i += stride) {
        float4 pv = p4[i];
        int4  gv = g4[i];
        int p0 = min(max(__float2int_rn(pv.x), 0), NUM_PRED);
        int p1 = min(max(__float2int_rn(pv.y), 0), NUM_PRED);
        int p2 = min(max(__float2int_rn(pv.z), 0), NUM_PRED);
        int p3 = min(max(__float2int_rn(pv.w), 0), NUM_PRED);
        int g0 = min(max(gv.x, 0), NUM_GT);
        int g1 = min(max(gv.y, 0), NUM_GT);
        int g2 = min(max(gv.z, 0), NUM_GT);
        int g3 = min(max(gv.w, 0), NUM_GT);

        gl[g0 * 64] += 1; pl[p0 * 64] += 1;
        gl[g1 * 64] += 1; pl[p1 * 64] += 1;
        gl[g2 * 64] += 1; pl[p2 * 64] += 1;
        gl[g3 * 64] += 1; pl[p3 * 64] += 1;

        unsigned b0 = 1u << g0; if (!(sovl[p0] & b0)) atomicOr(&sovl[p0], b0);
        unsigned b1 = 1u << g1; if (!(sovl[p1] & b1)) atomicOr(&sovl[p1], b1);
        unsigned b2 = 1u << g2; if (!(sovl[p2] & b2)) atomicOr(&sovl[p2], b2);
        unsigned b3 = 1u << g3; if (!(sovl[p3] & b3)) atomicOr(&sovl[p3], b3);
    }
    // tail (n divisible by 4 here; defensive)
    for (int i = (n4 << 2) + gtid; i < n; i += stride) {
        int p = min(max(__float2int_rn(pred[i]), 0), NUM_PRED);
        int g = min(max(gt[i], 0), NUM_GT);
        gl[g * 64] += 1; pl[p * 64] += 1;
        unsigned b = 1u << g; if (!(sovl[p] & b)) atomicOr(&sovl[p], b);
    }

    __syncthreads();

    // ---- block reduction: view u16 [wave][bin][64] as u32 [wave][bin][32] --
    // gt: 26 bins * 32 words; threads sharing bin b are 32 consecutive tids
    const unsigned int* s32g = (const unsigned int*)sgt;
    for (int i = tid; i < NGT1 * 32; i += BLOCK) {
        int b = i >> 5, w = i & 31;
        unsigned s = 0;
        #pragma unroll
        for (int wv = 0; wv < WAVES; ++wv) {
            unsigned x = s32g[(wv * NGT1 + b) * 32 + w];
            s += (x & 0xFFFFu) + (x >> 16);
        }
        s += __shfl_down(s, 16, 32);
        s += __shfl_down(s, 8, 32);
        s += __shfl_down(s, 4, 32);
        s += __shfl_down(s, 2, 32);
        s += __shfl_down(s, 1, 32);
        if (w == 0) atomicAdd(&ws[WS_GT + b], s);
    }
    const unsigned int* s32p = (const unsigned int*)spr;
    for (int i = tid; i < NPRED1 * 32; i += BLOCK) {
        int b = i >> 5, w = i & 31;
        unsigned s = 0;
        #pragma unroll
        for (int wv = 0; wv < WAVES; ++wv) {
            unsigned x = s32p[(wv * NPRED1 + b) * 32 + w];
            s += (x & 0xFFFFu) + (x >> 16);
        }
        s += __shfl_down(s, 16, 32);
        s += __shfl_down(s, 8, 32);
        s += __shfl_down(s, 4, 32);
        s += __shfl_down(s, 2, 32);
        s += __shfl_down(s, 1, 32);
        if (w == 0) atomicAdd(&ws[WS_PRED + b], s);
    }
    if (tid < NPRED1) {
        unsigned v = sovl[tid];
        if (v) atomicOr(&ws[WS_OVL + tid], v);
    }
}

// ---------------------------------------------------------------------------
// Kernel 2: parallel O(41*26) finisher, one wave, fp64 exact.
//   overlap[p][c] != 0 implies gt component c exists => tp_any[p] reduces to
//   (ovl[p] & bits 1..25) != 0.
// ---------------------------------------------------------------------------
__global__ __launch_bounds__(64) void finish_kernel(
    const unsigned int* __restrict__ ws, float* __restrict__ out)
{
    __shared__ double   ps[NPRED1];
    __shared__ unsigned ov[NPRED1];
    const int lane = threadIdx.x;
    if (lane < NPRED1) {
        ps[lane] = (double)ws[WS_PRED + lane];
        ov[lane] = ws[WS_OVL + lane];
    }
    __syncthreads();

    double dice = 0.0;
    int present = 0;
    if (lane < NUM_GT) {                     // gt component c = lane+1
        unsigned gs = ws[WS_GT + lane + 1];
        if (gs > 0) {
            present = 1;
            double un = 0.0;
            const unsigned bit = 1u << (lane + 1);
            for (int p = 0; p < NPRED1; ++p)
                if (ov[p] & bit) un += ps[p];
            dice = 2.0 * (double)gs / (un + (double)gs + 1.0);
        }
    }
    int fp = 0;
    if (lane < NPRED1) {
        // bits 1..25 of gt-label mask
        if (ws[WS_PRED + lane] > 0 && (ov[lane] & 0x3FFFFFEu) == 0) fp = 1;
    }

    int num_gt = __popcll(__ballot(present != 0));
    int nfp    = __popcll(__ballot(fp != 0));
    #pragma unroll
    for (int o = 32; o >= 1; o >>= 1) dice += __shfl_xor(dice, o, 64);

    if (lane == 0) out[0] = (float)(dice / (double)(num_gt + nfp));
}

extern "C" void kernel_launch(void* const* d_in, const int* in_sizes, int n_in,
                              void* d_out, int out_size, void* d_ws, size_t ws_size,
                              hipStream_t stream) {
    const float* pred = (const float*)d_in[0];
    const int* gt = (const int*)d_in[1];
    float* out = (float*)d_out;
    unsigned int* ws = (unsigned int*)d_ws;
    const int n = in_sizes[0];

    hipMemsetAsync(ws, 0, WS_WORDS * sizeof(unsigned int), stream);

    // 1024 blocks = 4 blocks/CU (LDS allows exactly 4 at 34.5 KB/block)
    hist_kernel<<<1024, BLOCK, 0, stream>>>(pred, gt, ws, n);
    finish_kernel<<<1, 64, 0, stream>>>(ws, out);
}

// Round 3
// 105.292 us; speedup vs baseline: 1.6712x; 1.6712x over previous
//
#include <hip/hip_runtime.h>
#include <hip/hip_bf16.h>

#define NUM_GT 25
#define NUM_PRED 40
#define NGT 25         // gt bins: labels 1..25 (label 0 never needed)
#define NPRED1 41      // pred bins: labels 0..40
#define NBINS 66       // 25 gt + 41 pred
#define PAD 32         // 32 u32 words = 128 B between global bins (L2-channel spread)

// global ws word offsets (each bin on its own 128B line)
#define GT_W(b)  ((b) * PAD)             // b = 0..24  <-> gt label b+1
#define PR_W(p)  ((25 + (p)) * PAD)      // p = 0..40
#define OV_W(p)  ((66 + (p)) * PAD)      // overlap bitmask row p
#define WS_WORDS (107 * PAD)

#define GRID 1024
#define BLOCK 256

// ---------------------------------------------------------------------------
// Histogram kernel: per-lane VGPR counters (zero LDS scatter in the hot loop).
// 66 compile-time-unrolled bins, increment = v_cmp + carry-add (2 VALU each).
// Overlap matrix via LDS test-then-set (read-only in steady state).
// ---------------------------------------------------------------------------
__global__ __launch_bounds__(BLOCK) void hist_kernel(
    const float* __restrict__ pred, const int* __restrict__ gt,
    unsigned int* __restrict__ ws, int n)
{
    __shared__ unsigned short cnt16[4][NBINS][64];   // 33,792 B (epilogue only)
    __shared__ unsigned int sovl[NPRED1];

    const int tid  = threadIdx.x;
    const int lane = tid & 63;
    const int wave = tid >> 6;

    if (tid < NPRED1) sovl[tid] = 0u;
    __syncthreads();

    unsigned int cgt[NGT];     // cgt[b] counts gt label b+1
    unsigned int cpr[NPRED1];  // cpr[p] counts pred label p
    #pragma unroll
    for (int b = 0; b < NGT; ++b) cgt[b] = 0u;
    #pragma unroll
    for (int p = 0; p < NPRED1; ++p) cpr[p] = 0u;

    const int gtid   = blockIdx.x * BLOCK + tid;
    const int stride = gridDim.x * BLOCK;
    const int n4 = n >> 2;
    const float4* __restrict__ p4 = (const float4*)pred;
    const int4* __restrict__  g4 = (const int4*)gt;

    for (int i = gtid; i < n4; i += stride) {
        float4 pv = p4[i];
        int4  gv = g4[i];
        // pred holds exact small integers in f32; truncation == round here
        int p0 = (int)pv.x, p1 = (int)pv.y, p2 = (int)pv.z, p3 = (int)pv.w;
        int g0 = gv.x, g1 = gv.y, g2 = gv.z, g3 = gv.w;

        // ---- overlap test-then-set (rarely taken after warm-up) ----
        int q0 = min(max(p0, 0), NUM_PRED);
        int q1 = min(max(p1, 0), NUM_PRED);
        int q2 = min(max(p2, 0), NUM_PRED);
        int q3 = min(max(p3, 0), NUM_PRED);
        unsigned b0 = 1u << (g0 & 31);
        unsigned b1 = 1u << (g1 & 31);
        unsigned b2 = 1u << (g2 & 31);
        unsigned b3 = 1u << (g3 & 31);
        if (!(sovl[q0] & b0)) atomicOr(&sovl[q0], b0);
        if (!(sovl[q1] & b1)) atomicOr(&sovl[q1], b1);
        if (!(sovl[q2] & b2)) atomicOr(&sovl[q2], b2);
        if (!(sovl[q3] & b3)) atomicOr(&sovl[q3], b3);

        // ---- register histogram: 2 VALU per (bin, slot) ----
        #pragma unroll
        for (int b = 0; b < NGT; ++b) {
            const int L = b + 1;
            cgt[b] += (unsigned)(g0 == L) + (unsigned)(g1 == L) +
                      (unsigned)(g2 == L) + (unsigned)(g3 == L);
        }
        #pragma unroll
        for (int p = 0; p < NPRED1; ++p) {
            cpr[p] += (unsigned)(p0 == p) + (unsigned)(p1 == p) +
                      (unsigned)(p2 == p) + (unsigned)(p3 == p);
        }
    }
    // scalar tail (n divisible by 4 here; defensive)
    for (int i = (n4 << 2) + gtid; i < n; i += stride) {
        int p = (int)pred[i];
        int g = gt[i];
        int q = min(max(p, 0), NUM_PRED);
        unsigned bb = 1u << (g & 31);
        if (!(sovl[q] & bb)) atomicOr(&sovl[q], bb);
        #pragma unroll
        for (int b = 0; b < NGT; ++b) cgt[b] += (unsigned)(g == b + 1);
        #pragma unroll
        for (int pp = 0; pp < NPRED1; ++pp) cpr[pp] += (unsigned)(p == pp);
    }

    // ---- epilogue: lane counters -> LDS u16 (max 64/lane-counter, fits) ----
    #pragma unroll
    for (int b = 0; b < NGT; ++b) cnt16[wave][b][lane] = (unsigned short)cgt[b];
    #pragma unroll
    for (int p = 0; p < NPRED1; ++p) cnt16[wave][NGT + p][lane] = (unsigned short)cpr[p];
    __syncthreads();

    // block reduction: u16 [4][66][64] viewed as u32 [4][66][32]
    const unsigned int* s32 = (const unsigned int*)cnt16;
    for (int i = tid; i < NBINS * 32; i += BLOCK) {
        int b = i >> 5, w = i & 31;
        unsigned s = 0;
        #pragma unroll
        for (int wv = 0; wv < 4; ++wv) {
            unsigned x = s32[(wv * NBINS + b) * 32 + w];
            s += (x & 0xFFFFu) + (x >> 16);
        }
        s += __shfl_down(s, 16, 32);
        s += __shfl_down(s, 8, 32);
        s += __shfl_down(s, 4, 32);
        s += __shfl_down(s, 2, 32);
        s += __shfl_down(s, 1, 32);
        if (w == 0 && s) atomicAdd(&ws[b * PAD], s);  // bins padded 128B apart
    }
    if (tid < NPRED1) {
        unsigned v = sovl[tid];
        if (v) atomicOr(&ws[OV_W(tid)], v);
    }
}

// ---------------------------------------------------------------------------
// Finisher: O(41*26), one wave, fp64 exact (proven absmax=0 in round 2).
// ---------------------------------------------------------------------------
__global__ __launch_bounds__(64) void finish_kernel(
    const unsigned int* __restrict__ ws, float* __restrict__ out)
{
    __shared__ double   ps[NPRED1];
    __shared__ unsigned ov[NPRED1];
    const int lane = threadIdx.x;
    if (lane < NPRED1) {
        ps[lane] = (double)ws[PR_W(lane)];
        ov[lane] = ws[OV_W(lane)];
    }
    __syncthreads();

    double dice = 0.0;
    int present = 0;
    if (lane < NGT) {                        // gt component label = lane+1
        unsigned gs = ws[GT_W(lane)];
        if (gs > 0) {
            present = 1;
            double un = 0.0;
            const unsigned bit = 1u << (lane + 1);
            for (int p = 0; p < NPRED1; ++p)
                if (ov[p] & bit) un += ps[p];
            dice = 2.0 * (double)gs / (un + (double)gs + 1.0);
        }
    }
    int fp = 0;
    if (lane < NPRED1) {
        if (ws[PR_W(lane)] > 0 && (ov[lane] & 0x3FFFFFEu) == 0) fp = 1;
    }

    int num_gt = __popcll(__ballot(present != 0));
    int nfp    = __popcll(__ballot(fp != 0));
    #pragma unroll
    for (int o = 32; o >= 1; o >>= 1) dice += __shfl_xor(dice, o, 64);

    if (lane == 0) out[0] = (float)(dice / (double)(num_gt + nfp));
}

extern "C" void kernel_launch(void* const* d_in, const int* in_sizes, int n_in,
                              void* d_out, int out_size, void* d_ws, size_t ws_size,
                              hipStream_t stream) {
    const float* pred = (const float*)d_in[0];
    const int* gt = (const int*)d_in[1];
    float* out = (float*)d_out;
    unsigned int* ws = (unsigned int*)d_ws;
    const int n = in_sizes[0];

    hipMemsetAsync(ws, 0, WS_WORDS * sizeof(unsigned int), stream);

    hist_kernel<<<GRID, BLOCK, 0, stream>>>(pred, gt, ws, n);
    finish_kernel<<<1, 64, 0, stream>>>(ws, out);
}

// Round 4
// 64.407 us; speedup vs baseline: 2.7321x; 1.6348x over previous
//
#include <hip/hip_runtime.h>
#include <hip/hip_bf16.h>

#define NUM_GT 25
#define NUM_PRED 40
#define NGT 25         // gt bins: labels 1..25
#define NPRED1 41      // pred bins: labels 0..40
#define NBINS 66       // 25 gt + 41 pred
#define PAD 32         // 128 B between global bins

#define GT_W(b)  ((b) * PAD)             // b = 0..24  <-> gt label b+1
#define PR_W(p)  ((25 + (p)) * PAD)      // p = 0..40
#define OV_W(p)  ((66 + (p)) * PAD)      // overlap bitmask row p
#define WS_WORDS (107 * PAD)

#define GRID 1024
#define BLOCK 256

// ---------------------------------------------------------------------------
// SWAR histogram: 4 labels byte-packed per u32; per bin B (K = B*0x01010101):
//   t = X ^ K           (bytes <= 0x7F since labels < 0x80)
//   t + 0x7F7F7F7F      bit7 of each byte = 1 iff byte != 0 (no carry)
//   cne[b] += (.. >> 7) & 0x01010101    packed NOT-EQUAL counts (<=16/byte)
// matches[b] = 4*iters - bytefold(cne[b]); 0x7F tail pads always mismatch.
// 5 VALU per (bin, 4 voxels) -- no vcc, no cndmask, no LDS in hot loop
// except the overlap test-then-set (steady-state read-only).
// ---------------------------------------------------------------------------
__global__ __launch_bounds__(BLOCK, 4) void hist_kernel(
    const float* __restrict__ pred, const int* __restrict__ gt,
    unsigned int* __restrict__ ws, int n)
{
    __shared__ unsigned short cnt16[4][NBINS][64];   // 33,792 B (epilogue only)
    __shared__ unsigned int sovl[64];

    const int tid  = threadIdx.x;
    const int lane = tid & 63;
    const int wave = tid >> 6;

    if (tid < 64) sovl[tid] = 0u;
    __syncthreads();

    unsigned cne[NBINS];               // packed per-byte not-equal counts
    #pragma unroll
    for (int b = 0; b < NBINS; ++b) cne[b] = 0u;

    const int gtid   = blockIdx.x * BLOCK + tid;
    const int stride = GRID * BLOCK;
    const int total4 = (n + 3) >> 2;
    const float4* __restrict__ p4 = (const float4*)pred;
    const int4* __restrict__  g4 = (const int4*)gt;

    unsigned iters = 0;

    for (int i = gtid; i < total4; i += stride) {
        unsigned p0, p1, p2, p3, g0, g1, g2, g3;
        if (((i << 2) | 3) < n) {
            float4 pv = p4[i];
            int4  gv = g4[i];
            p0 = (unsigned)pv.x; p1 = (unsigned)pv.y;
            p2 = (unsigned)pv.z; p3 = (unsigned)pv.w;
            g0 = (unsigned)gv.x; g1 = (unsigned)gv.y;
            g2 = (unsigned)gv.z; g3 = (unsigned)gv.w;
        } else {                         // tail pad: 0x7F matches no bin
            int base = i << 2;
            p0 = (base + 0 < n) ? (unsigned)pred[base + 0] : 0x7Fu;
            p1 = (base + 1 < n) ? (unsigned)pred[base + 1] : 0x7Fu;
            p2 = (base + 2 < n) ? (unsigned)pred[base + 2] : 0x7Fu;
            p3 = (base + 3 < n) ? (unsigned)pred[base + 3] : 0x7Fu;
            g0 = (base + 0 < n) ? (unsigned)gt[base + 0] : 0x7Fu;
            g1 = (base + 1 < n) ? (unsigned)gt[base + 1] : 0x7Fu;
            g2 = (base + 2 < n) ? (unsigned)gt[base + 2] : 0x7Fu;
            g3 = (base + 3 < n) ? (unsigned)gt[base + 3] : 0x7Fu;
        }
        ++iters;

        // ---- overlap test-then-set (rarely taken after warm-up) ----
        unsigned b0 = 1u << (g0 & 31), b1 = 1u << (g1 & 31);
        unsigned b2 = 1u << (g2 & 31), b3 = 1u << (g3 & 31);
        if (!(sovl[p0 & 63] & b0)) atomicOr(&sovl[p0 & 63], b0);
        if (!(sovl[p1 & 63] & b1)) atomicOr(&sovl[p1 & 63], b1);
        if (!(sovl[p2 & 63] & b2)) atomicOr(&sovl[p2 & 63], b2);
        if (!(sovl[p3 & 63] & b3)) atomicOr(&sovl[p3 & 63], b3);

        // ---- SWAR packed counting ----
        unsigned P4 = p0 | (p1 << 8) | (p2 << 16) | (p3 << 24);
        unsigned G4 = g0 | (g1 << 8) | (g2 << 16) | (g3 << 24);

        #pragma unroll
        for (int b = 0; b < NGT; ++b) {
            unsigned t = G4 ^ (0x01010101u * (unsigned)(b + 1));
            cne[b] += ((t + 0x7F7F7F7Fu) >> 7) & 0x01010101u;
        }
        #pragma unroll
        for (int p = 0; p < NPRED1; ++p) {
            unsigned t = P4 ^ (0x01010101u * (unsigned)p);
            cne[NGT + p] += ((t + 0x7F7F7F7Fu) >> 7) & 0x01010101u;
        }
    }

    // ---- per-lane matches -> LDS u16 (max 4*16 = 64, fits easily) ----
    const unsigned TV = iters * 4u;
    #pragma unroll
    for (int b = 0; b < NBINS; ++b) {
        unsigned c = cne[b];
        unsigned s = (c & 0x00FF00FFu) + ((c >> 8) & 0x00FF00FFu);
        s = (s & 0xFFFFu) + (s >> 16);
        cnt16[wave][b][lane] = (unsigned short)(TV - s);
    }
    __syncthreads();

    // ---- block reduction: u16 [4][66][64] viewed as u32 [4][66][32] ----
    const unsigned int* s32 = (const unsigned int*)cnt16;
    for (int i = tid; i < NBINS * 32; i += BLOCK) {
        int b = i >> 5, w = i & 31;
        unsigned s = 0;
        #pragma unroll
        for (int wv = 0; wv < 4; ++wv) {
            unsigned x = s32[(wv * NBINS + b) * 32 + w];
            s += (x & 0xFFFFu) + (x >> 16);
        }
        s += __shfl_down(s, 16, 32);
        s += __shfl_down(s, 8, 32);
        s += __shfl_down(s, 4, 32);
        s += __shfl_down(s, 2, 32);
        s += __shfl_down(s, 1, 32);
        if (w == 0 && s) atomicAdd(&ws[b * PAD], s);
    }
    if (tid < NPRED1) {
        unsigned v = sovl[tid];
        if (v) atomicOr(&ws[OV_W(tid)], v);
    }
}

// ---------------------------------------------------------------------------
// Finisher: O(41*26), one wave, fp64 exact (proven absmax=0).
// ---------------------------------------------------------------------------
__global__ __launch_bounds__(64) void finish_kernel(
    const unsigned int* __restrict__ ws, float* __restrict__ out)
{
    __shared__ double   ps[NPRED1];
    __shared__ unsigned ov[NPRED1];
    const int lane = threadIdx.x;
    if (lane < NPRED1) {
        ps[lane] = (double)ws[PR_W(lane)];
        ov[lane] = ws[OV_W(lane)];
    }
    __syncthreads();

    double dice = 0.0;
    int present = 0;
    if (lane < NGT) {                        // gt component label = lane+1
        unsigned gs = ws[GT_W(lane)];
        if (gs > 0) {
            present = 1;
            double un = 0.0;
            const unsigned bit = 1u << (lane + 1);
            for (int p = 0; p < NPRED1; ++p)
                if (ov[p] & bit) un += ps[p];
            dice = 2.0 * (double)gs / (un + (double)gs + 1.0);
        }
    }
    int fp = 0;
    if (lane < NPRED1) {
        if (ws[PR_W(lane)] > 0 && (ov[lane] & 0x3FFFFFEu) == 0) fp = 1;
    }

    int num_gt = __popcll(__ballot(present != 0));
    int nfp    = __popcll(__ballot(fp != 0));
    #pragma unroll
    for (int o = 32; o >= 1; o >>= 1) dice += __shfl_xor(dice, o, 64);

    if (lane == 0) out[0] = (float)(dice / (double)(num_gt + nfp));
}

extern "C" void kernel_launch(void* const* d_in, const int* in_sizes, int n_in,
                              void* d_out, int out_size, void* d_ws, size_t ws_size,
                              hipStream_t stream) {
    const float* pred = (const float*)d_in[0];
    const int* gt = (const int*)d_in[1];
    float* out = (float*)d_out;
    unsigned int* ws = (unsigned int*)d_ws;
    const int n = in_sizes[0];

    hipMemsetAsync(ws, 0, WS_WORDS * sizeof(unsigned int), stream);

    hist_kernel<<<GRID, BLOCK, 0, stream>>>(pred, gt, ws, n);
    finish_kernel<<<1, 64, 0, stream>>>(ws, out);
}